// Round 3
// baseline (1409.589 us; speedup 1.0000x reference)
//
#include <hip/hip_runtime.h>
#include <math.h>

#define T_STEPS 512
#define BATCH   64
#define DIM     1024
#define NB      16
#define NS      64
#define TOK     (T_STEPS*BATCH)        // 32768
#define SELROWS (2*TOK + NB*64)        // 66560 (spare rows for tile padding)
#define MAXTILES ((2*TOK)/64 + NB)     // 1040

// ---- workspace layout (float offsets) ----
#define WS_LOGITS 0                        // TOK*16
#define WS_W      (WS_LOGITS + TOK*NB)     // TOK*16 softmax weights
#define WS_Q      (WS_W + TOK*NB)          // TOK*64
#define WS_SEL    (WS_Q + TOK*NS)          // TOK ints (m1|m2<<8)
#define WS_TOKL   (WS_SEL + TOK)           // NB*TOK ints (per-block token lists)
#define WS_SELL   (WS_TOKL + NB*TOK)       // NB*TOK ints (per-block scatter rows)
#define WS_CNT    (WS_SELL + NB*TOK)       // 16 ints
#define WS_TILE   (WS_CNT + 16)            // 32 ints (tile prefix, [16]=total)
#define WS_KVSEL  (WS_TILE + 32)           // SELROWS*192 floats (k|v|beta+bias)

// ---------------- router logits, fp64 accumulate (top-k robustness) ----------
// 64-token tile, thread owns 2 toks x 2 blocks, fp32 LDS + fp64 accumulate.
#define LT 64
__global__ __launch_bounds__(256) void logits_kernel(
    const float* __restrict__ x, const float* __restrict__ Wr,
    float* __restrict__ logits)
{
  __shared__ __align__(16) float xsh[LT][36];
  __shared__ __align__(16) float wsh[NB][36];
  const int tid = threadIdx.x;
  const int cp  = tid & 7;        // c = 2cp, 2cp+1
  const int tp  = tid >> 3;       // toks = 2tp, 2tp+1
  const int tok0 = blockIdx.x * LT;
  double a00=0.0, a01=0.0, a10=0.0, a11=0.0;
  for (int k0 = 0; k0 < DIM; k0 += 32) {
    {
      int f = tid;
      #pragma unroll
      for (int e = 0; e < 2; e++, f += 256) {
        int r = f >> 3, c4 = (f & 7) << 2;
        *(float4*)&xsh[r][c4] = *(const float4*)&x[(size_t)(tok0 + r)*DIM + k0 + c4];
      }
      if (tid < 128) {
        int r = tid >> 3, c4 = (tid & 7) << 2;
        *(float4*)&wsh[r][c4] = *(const float4*)&Wr[(size_t)r*DIM + k0 + c4];
      }
    }
    __syncthreads();
    #pragma unroll
    for (int kk = 0; kk < 32; kk += 4) {
      float4 xa = *(const float4*)&xsh[2*tp+0][kk];
      float4 xb = *(const float4*)&xsh[2*tp+1][kk];
      float4 wa = *(const float4*)&wsh[2*cp+0][kk];
      float4 wb = *(const float4*)&wsh[2*cp+1][kk];
      a00 += (double)xa.x*wa.x + (double)xa.y*wa.y + (double)xa.z*wa.z + (double)xa.w*wa.w;
      a01 += (double)xa.x*wb.x + (double)xa.y*wb.y + (double)xa.z*wb.z + (double)xa.w*wb.w;
      a10 += (double)xb.x*wa.x + (double)xb.y*wa.y + (double)xb.z*wa.z + (double)xb.w*wa.w;
      a11 += (double)xb.x*wb.x + (double)xb.y*wb.y + (double)xb.z*wb.z + (double)xb.w*wb.w;
    }
    __syncthreads();
  }
  const size_t r0 = (size_t)(tok0 + 2*tp)*NB + 2*cp;
  logits[r0]          = (float)a00;
  logits[r0 + 1]      = (float)a01;
  logits[r0 + NB]     = (float)a10;
  logits[r0 + NB + 1] = (float)a11;
}

// ---------------- routing: top-2, softmax weights, bucket by block ----------
__global__ __launch_bounds__(256) void route_kernel(
    const float* __restrict__ logits, float* __restrict__ w,
    int* __restrict__ selp, int* __restrict__ toklist,
    int* __restrict__ sellist, int* __restrict__ cnt)
{
  const int tok = blockIdx.x*256 + threadIdx.x;
  const float* lg = logits + (size_t)tok*NB;
  float lv[NB];
  #pragma unroll
  for (int l = 0; l < NB; l++) lv[l] = lg[l];
  float v1 = lv[0]; int m1 = 0;
  #pragma unroll
  for (int l = 1; l < NB; l++) if (lv[l] > v1) { v1 = lv[l]; m1 = l; }
  float v2 = -3.4e38f; int m2 = 0;
  #pragma unroll
  for (int l = 0; l < NB; l++) if (l != m1 && lv[l] > v2) { v2 = lv[l]; m2 = l; }
  float ev[NB], sum = 0.f;
  #pragma unroll
  for (int l = 0; l < NB; l++) { ev[l] = __expf(lv[l] - v1); sum += ev[l]; }
  const float rs = __builtin_amdgcn_rcpf(sum);
  #pragma unroll
  for (int l = 0; l < NB; l++) w[(size_t)tok*NB + l] = ev[l] * rs;
  selp[tok] = m1 | (m2 << 8);
  int p1 = atomicAdd(&cnt[m1], 1);
  toklist[m1*TOK + p1] = tok;  sellist[m1*TOK + p1] = 2*tok;
  int p2 = atomicAdd(&cnt[m2], 1);
  toklist[m2*TOK + p2] = tok;  sellist[m2*TOK + p2] = 2*tok + 1;
}

// ---------------- tile prefix + pad tail tiles --------------------------------
__global__ void prefix_kernel(const int* __restrict__ cnt, int* __restrict__ tile,
                              int* __restrict__ toklist, int* __restrict__ sellist)
{
  __shared__ int off[NB+1];
  if (threadIdx.x == 0) {
    int a = 0;
    for (int c = 0; c < NB; c++) { off[c] = a; tile[c] = a; a += (cnt[c] + 63) >> 6; }
    off[NB] = a; tile[NB] = a;
  }
  __syncthreads();
  for (int c = 0; c < NB; c++) {
    const int s = cnt[c], e = (off[c+1] - off[c]) << 6;
    for (int i = s + threadIdx.x; i < e; i += 256) {
      toklist[c*TOK + i] = 0;
      sellist[c*TOK + i] = 2*TOK + c*64 + (i & 63);
    }
  }
}

// ---------------- gather-GEMM over selections ---------------------------------
__global__ __launch_bounds__(256) void gather_gemm_kernel(
    const float* __restrict__ x, const float* __restrict__ W_kv,
    const float* __restrict__ W_beta, const float* __restrict__ b_beta,
    const int* __restrict__ tileoff, const int* __restrict__ toklist,
    const int* __restrict__ sellist, float* __restrict__ kvsel)
{
  __shared__ __align__(16) float As[16][68];
  __shared__ __align__(16) float Bs[16][68];
  __shared__ int tl[64], sl[64];
  const int tile = blockIdx.x;
  if (tile >= tileoff[NB]) return;
  int c = 0;
  while (c < NB-1 && tile >= tileoff[c+1]) c++;
  const int ti = tile - tileoff[c];
  const int tid = threadIdx.x;
  if (tid < 64) {
    tl[tid] = toklist[c*TOK + (ti<<6) + tid];
    sl[tid] = sellist[c*TOK + (ti<<6) + tid];
  }
  __syncthreads();
  const int y = blockIdx.y;
  const float* Bp = (y < 2) ? (W_kv + ((size_t)c*128 + y*64)*DIM)
                            : (W_beta + (size_t)c*64*DIM);
  const int tx = tid & 15, ty = tid >> 4;
  const int lr = tid >> 2, lk = (tid & 3) << 2;
  const float* Ap = x + (size_t)tl[lr]*DIM;
  float acc[4][4] = {{0.f,0.f,0.f,0.f},{0.f,0.f,0.f,0.f},
                     {0.f,0.f,0.f,0.f},{0.f,0.f,0.f,0.f}};
  for (int k0 = 0; k0 < DIM; k0 += 16) {
    float4 a = *(const float4*)&Ap[k0 + lk];
    float4 b = *(const float4*)&Bp[(size_t)lr*DIM + k0 + lk];
    As[lk+0][lr]=a.x; As[lk+1][lr]=a.y; As[lk+2][lr]=a.z; As[lk+3][lr]=a.w;
    Bs[lk+0][lr]=b.x; Bs[lk+1][lr]=b.y; Bs[lk+2][lr]=b.z; Bs[lk+3][lr]=b.w;
    __syncthreads();
    #pragma unroll
    for (int kk = 0; kk < 16; kk++) {
      float4 av = *(const float4*)&As[kk][ty<<2];
      float4 bv = *(const float4*)&Bs[kk][tx<<2];
      acc[0][0] += av.x*bv.x; acc[0][1] += av.x*bv.y; acc[0][2] += av.x*bv.z; acc[0][3] += av.x*bv.w;
      acc[1][0] += av.y*bv.x; acc[1][1] += av.y*bv.y; acc[1][2] += av.y*bv.z; acc[1][3] += av.y*bv.w;
      acc[2][0] += av.z*bv.x; acc[2][1] += av.z*bv.y; acc[2][2] += av.z*bv.z; acc[2][3] += av.z*bv.w;
      acc[3][0] += av.w*bv.x; acc[3][1] += av.w*bv.y; acc[3][2] += av.w*bv.z; acc[3][3] += av.w*bv.w;
    }
    __syncthreads();
  }
  float4 bias = make_float4(0.f,0.f,0.f,0.f);
  if (y == 2) bias = *(const float4*)&b_beta[c*64 + (tx<<2)];
  #pragma unroll
  for (int u = 0; u < 4; u++) {
    const int srow = sl[(ty<<2) + u];
    *(float4*)&kvsel[(size_t)srow*192 + y*64 + (tx<<2)] =
        make_float4(acc[u][0]+bias.x, acc[u][1]+bias.y,
                    acc[u][2]+bias.z, acc[u][3]+bias.w);
  }
}

// ---------------- dense SGEMM for q ------------------------------------------
__global__ __launch_bounds__(256) void sgemm_kernel(
    const float* __restrict__ A, const float* __restrict__ B,
    float* __restrict__ C, int N, int K)
{
  __shared__ __align__(16) float As[16][68];
  __shared__ __align__(16) float Bs[16][68];
  const int tid = threadIdx.x;
  const int tx = tid & 15, ty = tid >> 4;
  const int m0 = blockIdx.x << 6, n0 = blockIdx.y << 6;
  const int lr = tid >> 2, lk = (tid & 3) << 2;
  float acc[4][4] = {{0.f,0.f,0.f,0.f},{0.f,0.f,0.f,0.f},
                     {0.f,0.f,0.f,0.f},{0.f,0.f,0.f,0.f}};
  for (int k0 = 0; k0 < K; k0 += 16) {
    float4 a = *(const float4*)&A[(size_t)(m0+lr)*K + k0 + lk];
    float4 b = *(const float4*)&B[(size_t)(n0+lr)*K + k0 + lk];
    As[lk+0][lr]=a.x; As[lk+1][lr]=a.y; As[lk+2][lr]=a.z; As[lk+3][lr]=a.w;
    Bs[lk+0][lr]=b.x; Bs[lk+1][lr]=b.y; Bs[lk+2][lr]=b.z; Bs[lk+3][lr]=b.w;
    __syncthreads();
    #pragma unroll
    for (int kk = 0; kk < 16; kk++) {
      float4 av = *(const float4*)&As[kk][ty<<2];
      float4 bv = *(const float4*)&Bs[kk][tx<<2];
      acc[0][0] += av.x*bv.x; acc[0][1] += av.x*bv.y; acc[0][2] += av.x*bv.z; acc[0][3] += av.x*bv.w;
      acc[1][0] += av.y*bv.x; acc[1][1] += av.y*bv.y; acc[1][2] += av.y*bv.z; acc[1][3] += av.y*bv.w;
      acc[2][0] += av.z*bv.x; acc[2][1] += av.z*bv.y; acc[2][2] += av.z*bv.z; acc[2][3] += av.z*bv.w;
      acc[3][0] += av.w*bv.x; acc[3][1] += av.w*bv.y; acc[3][2] += av.w*bv.z; acc[3][3] += av.w*bv.w;
    }
    __syncthreads();
  }
  #pragma unroll
  for (int u = 0; u < 4; u++)
    *(float4*)&C[(size_t)(m0 + (ty<<2) + u)*N + n0 + (tx<<2)] =
        make_float4(acc[u][0], acc[u][1], acc[u][2], acc[u][3]);
}

// ---------------- recurrence: TWO waves per (batch, block) --------------------
// wave w owns state columns [w*32, w*32+32); row = lane. 2 barriers on update
// steps, 1 otherwise. Parity-double-buffered LDS exchange.
__device__ __forceinline__ float fast_tanh(float v) {
  v = fminf(15.f, fmaxf(-15.f, v));
  float e = __expf(2.f*v);
  return (e - 1.f) * __builtin_amdgcn_rcpf(e + 1.f);
}

__global__ __launch_bounds__(128) void recur_kernel(
    const int* __restrict__ selp,     // [TOK] m1|m2<<8
    const float* __restrict__ w,      // [TOK][16]
    const float* __restrict__ kvsel,  // [SELROWS][192] k|v|beta_pre
    const float* __restrict__ qb,     // [TOK][64]
    float* __restrict__ out,          // [TOK][64] atomic accum (pre-zeroed)
    float* __restrict__ Sfin)         // [B][16][64][64]
{
  const int wv   = threadIdx.x >> 6;
  const int lane = threadIdx.x & 63;
  const int b = blockIdx.x >> 4, c = blockIdx.x & 15;
  const int half = wv << 5;
  __shared__ __align__(16) float knq[2][128];   // [parity][0:64 kn | 64:128 q]
  __shared__ __align__(16) float rp [2][2][64];
  __shared__ __align__(16) float sqp[2][2][64];

  float S[32];
  #pragma unroll
  for (int j = 0; j < 32; j++) S[j] = 0.f;

  auto sel = [&](int meta) -> bool {
    return c == (meta & 0xFF) || c == (meta >> 8);
  };
  auto loadkv = [&](int meta, int t, float& k, float& v, float& bp) {
    if (sel(meta)) {
      const size_t sidx = 2*(size_t)(t*BATCH + b) + ((c == (meta >> 8)) ? 1 : 0);
      const float* row = kvsel + sidx*192;
      if (wv == 0) k = row[lane];
      v = row[64 + lane]; bp = row[128 + lane];
    }
  };

  // pipeline preload: meta depth-3, data depth-2
  int   m_t  = selp[b], m_t1 = selp[BATCH + b], m_t2 = selp[2*BATCH + b];
  float wc_prev = 0.f, wc_t = 0.f, wc_t1 = 0.f;
  float q_t = 0.f, q_t1 = 0.f;
  if (wv == 0) {
    wc_t = w[(size_t)b*NB + c]; wc_t1 = w[(size_t)(BATCH + b)*NB + c];
    q_t  = qb[(size_t)b*NS + lane]; q_t1 = qb[(size_t)(BATCH + b)*NS + lane];
  }
  float k_t=0.f, v_t=0.f, bp_t=0.f, k_t1=0.f, v_t1=0.f, bp_t1=0.f;
  loadkv(m_t, 0, k_t, v_t, bp_t);
  loadkv(m_t1, 1, k_t1, v_t1, bp_t1);

  #pragma unroll 2
  for (int t = 0; t < T_STEPS; t++) {
    const int p = t & 1;
    const int tn  = (t+2 < T_STEPS) ? t+2 : T_STEPS-1;
    const int tn3 = (t+3 < T_STEPS) ? t+3 : T_STEPS-1;
    // prefetches
    const int m_t3 = selp[tn3*BATCH + b];
    float wc_t2 = 0.f, q_t2 = 0.f;
    if (wv == 0) {
      wc_t2 = w[(size_t)(tn*BATCH + b)*NB + c];
      q_t2  = qb[(size_t)(tn*BATCH + b)*NS + lane];
    }
    float k_t2=0.f, v_t2=0.f, bp_t2=0.f;
    loadkv(m_t2, tn, k_t2, v_t2, bp_t2);

    const bool s = sel(m_t);
    // wave0: kn + q broadcast into LDS
    if (wv == 0) {
      if (s) {
        float s2 = k_t*k_t;
        #pragma unroll
        for (int off = 32; off; off >>= 1) s2 += __shfl_xor(s2, off);
        const float kn = k_t * __builtin_amdgcn_rcpf(sqrtf(s2) + 1e-6f);
        knq[p][lane] = kn;
      }
      knq[p][64 + lane] = q_t;
    }
    __syncthreads();   // B1
    // wave0: finalize step t-1 output
    if (wv == 0 && t > 0) {
      const float sqv = sqp[p^1][0][lane] + sqp[p^1][1][lane];
      const float bo = sqv*sqv * __builtin_amdgcn_rcpf(1.f + __expf(-sqv));
      unsafeAtomicAdd(&out[(size_t)((t-1)*BATCH + b)*NS + lane], wc_prev*bo);
    }
    if (s) {
      // r partial over own 32 columns
      float a0=0.f,a1=0.f,a2=0.f,a3=0.f;
      #pragma unroll
      for (int j = 0; j < 32; j += 4) {
        float4 k4 = *(const float4*)&knq[p][half + j];
        a0 = fmaf(S[j],   k4.x, a0); a1 = fmaf(S[j+1], k4.y, a1);
        a2 = fmaf(S[j+2], k4.z, a2); a3 = fmaf(S[j+3], k4.w, a3);
      }
      rp[p][wv][lane] = (a0+a1)+(a2+a3);
      __syncthreads(); // B2
      const float r = rp[p][0][lane] + rp[p][1][lane];
      const float beta  = __builtin_amdgcn_rcpf(1.f + __expf(-bp_t));
      const float delta = v_t - r;
      #pragma unroll
      for (int j = 0; j < 32; j += 4) {
        float4 k4 = *(const float4*)&knq[p][half + j];
        S[j+0] = fast_tanh(beta*S[j+0] + delta*k4.x);
        S[j+1] = fast_tanh(beta*S[j+1] + delta*k4.y);
        S[j+2] = fast_tanh(beta*S[j+2] + delta*k4.z);
        S[j+3] = fast_tanh(beta*S[j+3] + delta*k4.w);
      }
    }
    // Sq partial over own 32 columns
    {
      float a0=0.f,a1=0.f,a2=0.f,a3=0.f;
      #pragma unroll
      for (int j = 0; j < 32; j += 4) {
        float4 q4 = *(const float4*)&knq[p][64 + half + j];
        a0 = fmaf(S[j],   q4.x, a0); a1 = fmaf(S[j+1], q4.y, a1);
        a2 = fmaf(S[j+2], q4.z, a2); a3 = fmaf(S[j+3], q4.w, a3);
      }
      sqp[p][wv][lane] = (a0+a1)+(a2+a3);
    }
    // rotate pipeline
    m_t = m_t1; m_t1 = m_t2; m_t2 = m_t3;
    wc_prev = wc_t; wc_t = wc_t1; wc_t1 = wc_t2;
    q_t = q_t1;  q_t1 = q_t2;
    k_t = k_t1;  v_t = v_t1;  bp_t = bp_t1;
    k_t1 = k_t2; v_t1 = v_t2; bp_t1 = bp_t2;
  }

  __syncthreads();
  if (wv == 0) {
    const int pl = (T_STEPS-1) & 1;
    const float sqv = sqp[pl][0][lane] + sqp[pl][1][lane];
    const float bo = sqv*sqv * __builtin_amdgcn_rcpf(1.f + __expf(-sqv));
    unsafeAtomicAdd(&out[(size_t)((T_STEPS-1)*BATCH + b)*NS + lane], wc_prev*bo);
  }

  float* dst = Sfin + (((size_t)b*NB + c)*NS + lane)*NS + half;
  #pragma unroll
  for (int j = 0; j < 32; j += 4)
    *(float4*)&dst[j] = make_float4(S[j], S[j+1], S[j+2], S[j+3]);
}

extern "C" void kernel_launch(void* const* d_in, const int* in_sizes, int n_in,
                              void* d_out, int out_size, void* d_ws, size_t ws_size,
                              hipStream_t stream) {
  const float* x        = (const float*)d_in[0];
  const float* W_router = (const float*)d_in[1];
  const float* W_kv     = (const float*)d_in[2];
  const float* W_beta   = (const float*)d_in[3];
  const float* b_beta   = (const float*)d_in[4];
  const float* W_q      = (const float*)d_in[5];

  float* out  = (float*)d_out;
  float* Sfin = out + (size_t)TOK*NS;
  float* ws     = (float*)d_ws;
  float* logits = ws + WS_LOGITS;
  float* wsm    = ws + WS_W;
  float* qb     = ws + WS_Q;
  int*   selp   = (int*)(ws + WS_SEL);
  int*   toklist= (int*)(ws + WS_TOKL);
  int*   sellist= (int*)(ws + WS_SELL);
  int*   cnt    = (int*)(ws + WS_CNT);
  int*   tile   = (int*)(ws + WS_TILE);
  float* kvsel  = ws + WS_KVSEL;

  hipMemsetAsync(out, 0, (size_t)TOK*NS*sizeof(float), stream);
  hipMemsetAsync(cnt, 0, 16*sizeof(int), stream);

  logits_kernel<<<TOK/LT, 256, 0, stream>>>(x, W_router, logits);
  sgemm_kernel<<<dim3(TOK/64, 1), 256, 0, stream>>>(x, W_q, qb, NS, DIM);
  route_kernel<<<TOK/256, 256, 0, stream>>>(logits, wsm, selp, toklist, sellist, cnt);
  prefix_kernel<<<1, 256, 0, stream>>>(cnt, tile, toklist, sellist);
  gather_gemm_kernel<<<dim3(MAXTILES, 3), 256, 0, stream>>>(
      x, W_kv, W_beta, b_beta, tile, toklist, sellist, kvsel);
  recur_kernel<<<BATCH*NB, 128, 0, stream>>>(selp, wsm, kvsel, qb, out, Sfin);
}

// Round 4
// 1313.309 us; speedup vs baseline: 1.0733x; 1.0733x over previous
//
#include <hip/hip_runtime.h>
#include <hip/hip_bf16.h>
#include <math.h>

#define T_STEPS 512
#define BATCH   64
#define DIM     1024
#define NB      16
#define NS      64
#define TOK     (T_STEPS*BATCH)        // 32768
#define SELROWS (2*TOK + NB*64)        // 66560 (spare rows for tile padding)
#define MAXTILES ((2*TOK)/64 + NB)     // 1040

// ---- workspace layout (float offsets) ----
#define WS_LOGITS 0                        // TOK*16
#define WS_W      (WS_LOGITS + TOK*NB)     // TOK*16 softmax weights
#define WS_Q      (WS_W + TOK*NB)          // TOK*64
#define WS_SEL    (WS_Q + TOK*NS)          // TOK ints (m1|m2<<8)
#define WS_TOKL   (WS_SEL + TOK)           // NB*TOK ints
#define WS_SELL   (WS_TOKL + NB*TOK)       // NB*TOK ints
#define WS_CNT    (WS_SELL + NB*TOK)       // 16 ints
#define WS_TILE   (WS_CNT + 16)            // 32 ints
#define WS_KVSEL  (WS_TILE + 32)           // SELROWS*192 floats
#define WS_WHI    (WS_KVSEL + SELROWS*192) // 16*192*1024 bf16 = 1572864 float-slots
#define WS_WLO    (WS_WHI + (NB*192*DIM)/2)
// end = WS_WLO + (NB*192*DIM)/2  ~ 20.2M floats ~ 81 MB

typedef __attribute__((ext_vector_type(8))) short short8x;
typedef __attribute__((ext_vector_type(4))) float f32x4;

__device__ __forceinline__ short f2bf_hi(float f, float& rem) {
  __hip_bfloat16 h = __float2bfloat16(f);
  rem = f - __bfloat162float(h);
  return *(short*)&h;
}
__device__ __forceinline__ short f2bf(float f) {
  __hip_bfloat16 h = __float2bfloat16(f);
  return *(short*)&h;
}
__device__ __forceinline__ float sigm(float x) {
  return __builtin_amdgcn_rcpf(1.f + __builtin_amdgcn_exp2f(-1.4426950408889634f*x));
}
__device__ __forceinline__ float fast_tanh(float v) {
  v = fminf(10.f, fmaxf(-10.f, v));
  float e = __builtin_amdgcn_exp2f(2.8853900817779268f*v);
  return 1.f - 2.f*__builtin_amdgcn_rcpf(e + 1.f);
}

// ---------------- router logits: fp64, no LDS, W broadcast ------------------
// grid TOK/64 blocks x 256 thr; wave wv -> blocks 4wv..4wv+3; lane = token.
__global__ __launch_bounds__(256) void logits_kernel(
    const float* __restrict__ x, const float* __restrict__ Wr,
    float* __restrict__ logits)
{
  const int wv   = __builtin_amdgcn_readfirstlane(threadIdx.x >> 6);
  const int lane = threadIdx.x & 63;
  const int tok  = blockIdx.x*64 + lane;
  const float* xr = x + (size_t)tok*DIM;
  const float* w0 = Wr + (size_t)(4*wv)*DIM;
  double acc[4] = {0.0, 0.0, 0.0, 0.0};
  for (int k0 = 0; k0 < DIM; k0 += 32) {
    float4 xv[8];
    #pragma unroll
    for (int i = 0; i < 8; i++) xv[i] = *(const float4*)&xr[k0 + 4*i];
    #pragma unroll
    for (int cc = 0; cc < 4; cc++) {
      const float* wr = w0 + (size_t)cc*DIM + k0;
      double s = 0.0;
      #pragma unroll
      for (int i = 0; i < 8; i++) {
        float4 w4 = *(const float4*)&wr[4*i];
        s += ((double)xv[i].x*(double)w4.x + (double)xv[i].y*(double)w4.y)
           + ((double)xv[i].z*(double)w4.z + (double)xv[i].w*(double)w4.w);
      }
      acc[cc] += s;
    }
  }
  #pragma unroll
  for (int cc = 0; cc < 4; cc++)
    logits[(size_t)tok*NB + 4*wv + cc] = (float)acc[cc];
}

// ---------------- routing (unchanged) ---------------------------------------
__global__ __launch_bounds__(256) void route_kernel(
    const float* __restrict__ logits, float* __restrict__ w,
    int* __restrict__ selp, int* __restrict__ toklist,
    int* __restrict__ sellist, int* __restrict__ cnt)
{
  const int tok = blockIdx.x*256 + threadIdx.x;
  const float* lg = logits + (size_t)tok*NB;
  float lv[NB];
  #pragma unroll
  for (int l = 0; l < NB; l++) lv[l] = lg[l];
  float v1 = lv[0]; int m1 = 0;
  #pragma unroll
  for (int l = 1; l < NB; l++) if (lv[l] > v1) { v1 = lv[l]; m1 = l; }
  float v2 = -3.4e38f; int m2 = 0;
  #pragma unroll
  for (int l = 0; l < NB; l++) if (l != m1 && lv[l] > v2) { v2 = lv[l]; m2 = l; }
  float ev[NB], sum = 0.f;
  #pragma unroll
  for (int l = 0; l < NB; l++) { ev[l] = __expf(lv[l] - v1); sum += ev[l]; }
  const float rs = __builtin_amdgcn_rcpf(sum);
  #pragma unroll
  for (int l = 0; l < NB; l++) w[(size_t)tok*NB + l] = ev[l] * rs;
  selp[tok] = m1 | (m2 << 8);
  int p1 = atomicAdd(&cnt[m1], 1);
  toklist[m1*TOK + p1] = tok;  sellist[m1*TOK + p1] = 2*tok;
  int p2 = atomicAdd(&cnt[m2], 1);
  toklist[m2*TOK + p2] = tok;  sellist[m2*TOK + p2] = 2*tok + 1;
}

// ---------------- tile prefix + pad tail tiles (unchanged) -------------------
__global__ void prefix_kernel(const int* __restrict__ cnt, int* __restrict__ tile,
                              int* __restrict__ toklist, int* __restrict__ sellist)
{
  __shared__ int off[NB+1];
  if (threadIdx.x == 0) {
    int a = 0;
    for (int c = 0; c < NB; c++) { off[c] = a; tile[c] = a; a += (cnt[c] + 63) >> 6; }
    off[NB] = a; tile[NB] = a;
  }
  __syncthreads();
  for (int c = 0; c < NB; c++) {
    const int s = cnt[c], e = (off[c+1] - off[c]) << 6;
    for (int i = s + threadIdx.x; i < e; i += 256) {
      toklist[c*TOK + i] = 0;
      sellist[c*TOK + i] = 2*TOK + c*64 + (i & 63);
    }
  }
}

// ---------------- W split-cast: fp32 -> bf16 hi/lo, per-block row layout -----
// row R = c*192 + r: r<128 -> W_kv[c*128+r], else W_beta[c*64+(r-128)]
__global__ void wcast_kernel(const float* __restrict__ Wkv,
                             const float* __restrict__ Wb,
                             short* __restrict__ Whi, short* __restrict__ Wlo)
{
  const int R = blockIdx.x, c = R/192, r = R%192;
  const float* src = (r < 128) ? Wkv + ((size_t)c*128 + r)*DIM
                               : Wb  + ((size_t)c*64 + (r-128))*DIM;
  const int k = threadIdx.x*4;
  float4 f = *(const float4*)&src[k];
  float ff[4] = {f.x, f.y, f.z, f.w};
  short* dh = Whi + (size_t)R*DIM + k;
  short* dl = Wlo + (size_t)R*DIM + k;
  #pragma unroll
  for (int e = 0; e < 4; e++) {
    float rem;
    dh[e] = f2bf_hi(ff[e], rem);
    dl[e] = f2bf(rem);
  }
}

// ---------------- gather-GEMM: bf16x3 MFMA ----------------------------------
// block = one 64-row sel tile, all 192 outputs. 4 waves x 48-col strips.
__global__ __launch_bounds__(256) void gather_gemm_kernel(
    const float* __restrict__ x,
    const short* __restrict__ Whi, const short* __restrict__ Wlo,
    const float* __restrict__ b_beta,
    const int* __restrict__ tileoff, const int* __restrict__ toklist,
    const int* __restrict__ sellist, float* __restrict__ kvsel)
{
  __shared__ short Ahi[64][40];   // 32 k + 8 pad (2-way bank max)
  __shared__ short Alo[64][40];
  __shared__ int tl[64], sl[64];
  const int tile = blockIdx.x;
  if (tile >= tileoff[NB]) return;
  int c = 0;
  while (c < NB-1 && tile >= tileoff[c+1]) c++;
  const int ti = tile - tileoff[c];
  const int tid = threadIdx.x;
  if (tid < 64) {
    tl[tid] = toklist[c*TOK + (ti<<6) + tid];
    sl[tid] = sellist[c*TOK + (ti<<6) + tid];
  }
  __syncthreads();

  const int wv = tid >> 6, l = tid & 63;
  const int arow = tid >> 2, akseg = (tid & 3) << 3;   // stage: row, 8-k seg
  const float* aptr = x + (size_t)tl[arow]*DIM + akseg;
  const short* bh_p = Whi + ((size_t)c*192 + wv*48 + (l & 15))*DIM + ((l >> 4) << 3);
  const short* bl_p = Wlo + ((size_t)c*192 + wv*48 + (l & 15))*DIM + ((l >> 4) << 3);

  f32x4 acc[4][3];
  #pragma unroll
  for (int mt = 0; mt < 4; mt++)
    #pragma unroll
    for (int nt = 0; nt < 3; nt++) acc[mt][nt] = (f32x4){0.f,0.f,0.f,0.f};

  // ping-pong prefetch buffers
  float4 af[2][2];
  short8x bh[2][3], bl[2][3];
  af[0][0] = *(const float4*)&aptr[0];
  af[0][1] = *(const float4*)&aptr[4];
  #pragma unroll
  for (int nt = 0; nt < 3; nt++) {
    bh[0][nt] = *(const short8x*)&bh_p[nt*16*DIM];
    bl[0][nt] = *(const short8x*)&bl_p[nt*16*DIM];
  }

  #pragma unroll 2
  for (int ch = 0; ch < 32; ch++) {
    const int p = ch & 1, pn = p ^ 1;
    // cast + stage A chunk ch
    {
      float f8[8] = {af[p][0].x, af[p][0].y, af[p][0].z, af[p][0].w,
                     af[p][1].x, af[p][1].y, af[p][1].z, af[p][1].w};
      short h8[8], l8[8];
      #pragma unroll
      for (int e = 0; e < 8; e++) {
        float rem;
        h8[e] = f2bf_hi(f8[e], rem);
        l8[e] = f2bf(rem);
      }
      *(short8x*)&Ahi[arow][akseg] = *(short8x*)h8;
      *(short8x*)&Alo[arow][akseg] = *(short8x*)l8;
    }
    // prefetch A for ch+1
    if (ch < 31) {
      af[pn][0] = *(const float4*)&aptr[(ch+1)*32];
      af[pn][1] = *(const float4*)&aptr[(ch+1)*32 + 4];
    }
    __syncthreads();
    // prefetch B for ch+1
    if (ch < 31) {
      #pragma unroll
      for (int nt = 0; nt < 3; nt++) {
        bh[pn][nt] = *(const short8x*)&bh_p[nt*16*DIM + (ch+1)*32];
        bl[pn][nt] = *(const short8x*)&bl_p[nt*16*DIM + (ch+1)*32];
      }
    }
    // A frags
    short8x ah[4], al[4];
    #pragma unroll
    for (int mt = 0; mt < 4; mt++) {
      ah[mt] = *(const short8x*)&Ahi[mt*16 + (l & 15)][(l >> 4) << 3];
      al[mt] = *(const short8x*)&Alo[mt*16 + (l & 15)][(l >> 4) << 3];
    }
    // bf16x3 MFMA
    #pragma unroll
    for (int mt = 0; mt < 4; mt++)
      #pragma unroll
      for (int nt = 0; nt < 3; nt++) {
        acc[mt][nt] = __builtin_amdgcn_mfma_f32_16x16x32_bf16(ah[mt], bh[p][nt], acc[mt][nt], 0, 0, 0);
        acc[mt][nt] = __builtin_amdgcn_mfma_f32_16x16x32_bf16(ah[mt], bl[p][nt], acc[mt][nt], 0, 0, 0);
        acc[mt][nt] = __builtin_amdgcn_mfma_f32_16x16x32_bf16(al[mt], bh[p][nt], acc[mt][nt], 0, 0, 0);
      }
    __syncthreads();
  }

  // epilogue: D layout col=l&15, row=(l>>4)*4+reg
  #pragma unroll
  for (int mt = 0; mt < 4; mt++) {
    #pragma unroll
    for (int reg = 0; reg < 4; reg++) {
      const int row = mt*16 + (l >> 4)*4 + reg;
      const int srow = sl[row];
      #pragma unroll
      for (int nt = 0; nt < 3; nt++) {
        const int col = wv*48 + nt*16 + (l & 15);
        float vvv = acc[mt][nt][reg];
        if (col >= 128) vvv += b_beta[c*64 + (col - 128)];
        kvsel[(size_t)srow*192 + col] = vvv;
      }
    }
  }
}

// ---------------- dense fp32 SGEMM for q (small, unchanged) ------------------
__global__ __launch_bounds__(256) void sgemm_kernel(
    const float* __restrict__ A, const float* __restrict__ B,
    float* __restrict__ C, int N, int K)
{
  __shared__ __align__(16) float As[16][68];
  __shared__ __align__(16) float Bs[16][68];
  const int tid = threadIdx.x;
  const int tx = tid & 15, ty = tid >> 4;
  const int m0 = blockIdx.x << 6, n0 = blockIdx.y << 6;
  const int lr = tid >> 2, lk = (tid & 3) << 2;
  float acc[4][4] = {{0.f,0.f,0.f,0.f},{0.f,0.f,0.f,0.f},
                     {0.f,0.f,0.f,0.f},{0.f,0.f,0.f,0.f}};
  for (int k0 = 0; k0 < K; k0 += 16) {
    float4 a = *(const float4*)&A[(size_t)(m0+lr)*K + k0 + lk];
    float4 b = *(const float4*)&B[(size_t)(n0+lr)*K + k0 + lk];
    As[lk+0][lr]=a.x; As[lk+1][lr]=a.y; As[lk+2][lr]=a.z; As[lk+3][lr]=a.w;
    Bs[lk+0][lr]=b.x; Bs[lk+1][lr]=b.y; Bs[lk+2][lr]=b.z; Bs[lk+3][lr]=b.w;
    __syncthreads();
    #pragma unroll
    for (int kk = 0; kk < 16; kk++) {
      float4 av = *(const float4*)&As[kk][ty<<2];
      float4 bv = *(const float4*)&Bs[kk][tx<<2];
      acc[0][0] += av.x*bv.x; acc[0][1] += av.x*bv.y; acc[0][2] += av.x*bv.z; acc[0][3] += av.x*bv.w;
      acc[1][0] += av.y*bv.x; acc[1][1] += av.y*bv.y; acc[1][2] += av.y*bv.z; acc[1][3] += av.y*bv.w;
      acc[2][0] += av.z*bv.x; acc[2][1] += av.z*bv.y; acc[2][2] += av.z*bv.z; acc[2][3] += av.z*bv.w;
      acc[3][0] += av.w*bv.x; acc[3][1] += av.w*bv.y; acc[3][2] += av.w*bv.z; acc[3][3] += av.w*bv.w;
    }
    __syncthreads();
  }
  #pragma unroll
  for (int u = 0; u < 4; u++)
    *(float4*)&C[(size_t)(m0 + (ty<<2) + u)*N + n0 + (tx<<2)] =
        make_float4(acc[u][0], acc[u][1], acc[u][2], acc[u][3]);
}

// ---------------- recurrence: 1 wave per (b,c), deep pipeline ----------------
__global__ __launch_bounds__(256, 1) void recur_kernel(
    const int* __restrict__ selp,     // [TOK] m1|m2<<8
    const float* __restrict__ w,      // [TOK][16]
    const float* __restrict__ kvsel,  // [SELROWS][192]
    const float* __restrict__ qb,     // [TOK][64]
    float* __restrict__ out,          // [TOK][64] atomic accum (pre-zeroed)
    float* __restrict__ Sfin)         // [B][16][64][64]
{
  const int wv = threadIdx.x >> 6, lane = threadIdx.x & 63;
  const int task = blockIdx.x*4 + wv, b = task >> 4, c = task & 15;
  __shared__ __align__(16) float ldsQ[4][2][64];
  __shared__ __align__(16) float ldsK[4][2][64];

  float S[NS];
  #pragma unroll
  for (int j = 0; j < NS; j++) S[j] = 0.f;

  // running pointers (t-stride in elements)
  const int*   sp = selp + b;                        // stride 64
  const float* wp = w  + (size_t)b*NB + c;           // stride 1024
  const float* qp = qb + (size_t)b*NS + lane;        // stride 4096
  float*       op = out + (size_t)b*NS + lane;       // stride 4096

  int   m[8];
  float kk[4], vv[4], bb[4], qq[4], wc[4], bet[2];
  #pragma unroll
  for (int i = 0; i < 8; i++) m[i] = 0;

  #pragma unroll
  for (int i = 0; i < 5; i++)
    m[i] = __builtin_amdgcn_readfirstlane(sp[(size_t)i*64]);
  #pragma unroll
  for (int i = 0; i < 3; i++) {
    qq[i] = qp[(size_t)i*4096];
    wc[i] = wp[(size_t)i*1024];
    kk[i] = vv[i] = bb[i] = 0.f;
    const int mm = m[i];
    if (c == (mm & 255) || c == (mm >> 8)) {
      const float* r = kvsel + ((size_t)2*(i*BATCH + b) + ((c == (mm >> 8)) ? 1 : 0))*192;
      kk[i] = r[lane]; vv[i] = r[64 + lane]; bb[i] = r[128 + lane];
    }
  }
  bet[0] = bet[1] = 0.f;
  // stage slot for t=0
  ldsQ[wv][0][lane] = qq[0];
  {
    const int mm = m[0];
    if (c == (mm & 255) || c == (mm >> 8)) {
      float s2 = kk[0]*kk[0];
      #pragma unroll
      for (int o = 32; o; o >>= 1) s2 += __shfl_xor(s2, o);
      ldsK[wv][0][lane] = kk[0]*__builtin_amdgcn_rcpf(sqrtf(s2) + 1e-6f);
      bet[0] = sigm(bb[0]);
    }
  }

  #pragma unroll 2
  for (int t = 0; t < T_STEPS; t++) {
    const int i0 = t & 3, i1 = (t+1) & 3, i3 = (t+3) & 3;
    // ---- prefetch: meta t+5, data t+3 (over-reads land in allocated ws) ----
    m[(t+5) & 7] = __builtin_amdgcn_readfirstlane(sp[(size_t)(t+5)*64]);
    qq[i3] = qp[(size_t)(t+3)*4096];
    wc[i3] = wp[(size_t)(t+3)*1024];
    {
      const int mm = m[(t+3) & 7];
      kk[i3] = vv[i3] = bb[i3] = 0.f;
      if (c == (mm & 255) || c == (mm >> 8)) {
        const float* r = kvsel + ((size_t)2*((t+3)*BATCH + b) + ((c == (mm >> 8)) ? 1 : 0))*192;
        kk[i3] = r[lane]; vv[i3] = r[64 + lane]; bb[i3] = r[128 + lane];
      }
    }
    // ---- stage t+1 (k loaded 2 iters ago: norm chain off critical path) ----
    ldsQ[wv][(t+1) & 1][lane] = qq[i1];
    {
      const int mm = m[(t+1) & 7];
      if (c == (mm & 255) || c == (mm >> 8)) {
        float s2 = kk[i1]*kk[i1];
        #pragma unroll
        for (int o = 32; o; o >>= 1) s2 += __shfl_xor(s2, o);
        ldsK[wv][(t+1) & 1][lane] = kk[i1]*__builtin_amdgcn_rcpf(sqrtf(s2) + 1e-6f);
        bet[(t+1) & 1] = sigm(bb[i1]);
      }
    }
    // ---- compute step t ----
    {
      const int mm = m[t & 7];
      if (c == (mm & 255) || c == (mm >> 8)) {
        const float* kr = &ldsK[wv][t & 1][0];
        float aa[4] = {0.f, 0.f, 0.f, 0.f};
        #pragma unroll
        for (int j = 0; j < NS; j += 4) {
          float4 k4 = *(const float4*)&kr[j];
          const int ai = (j >> 2) & 3;
          aa[ai] = fmaf(S[j+3], k4.w, fmaf(S[j+2], k4.z,
                   fmaf(S[j+1], k4.y, fmaf(S[j+0], k4.x, aa[ai]))));
        }
        const float r = (aa[0] + aa[1]) + (aa[2] + aa[3]);
        const float g = vv[i0] - r;
        const float be = bet[t & 1];
        #pragma unroll
        for (int j = 0; j < NS; j += 4) {
          float4 k4 = *(const float4*)&kr[j];
          S[j+0] = fast_tanh(fmaf(be, S[j+0], g*k4.x));
          S[j+1] = fast_tanh(fmaf(be, S[j+1], g*k4.y));
          S[j+2] = fast_tanh(fmaf(be, S[j+2], g*k4.z));
          S[j+3] = fast_tanh(fmaf(be, S[j+3], g*k4.w));
        }
      }
    }
    // ---- output: Sq, silu-gate, atomic accumulate ----
    {
      const float* qr = &ldsQ[wv][t & 1][0];
      float aa[4] = {0.f, 0.f, 0.f, 0.f};
      #pragma unroll
      for (int j = 0; j < NS; j += 4) {
        float4 q4 = *(const float4*)&qr[j];
        const int ai = (j >> 2) & 3;
        aa[ai] = fmaf(S[j+3], q4.w, fmaf(S[j+2], q4.z,
                 fmaf(S[j+1], q4.y, fmaf(S[j+0], q4.x, aa[ai]))));
      }
      const float sq = (aa[0] + aa[1]) + (aa[2] + aa[3]);
      const float bo = sq*sq*sigm(sq);
      unsafeAtomicAdd(&op[(size_t)t*4096], wc[i0]*bo);
    }
  }

  float* dst = Sfin + (((size_t)b*NB + c)*NS + lane)*NS;
  #pragma unroll
  for (int j = 0; j < NS; j += 4)
    *(float4*)&dst[j] = make_float4(S[j], S[j+1], S[j+2], S[j+3]);
}

extern "C" void kernel_launch(void* const* d_in, const int* in_sizes, int n_in,
                              void* d_out, int out_size, void* d_ws, size_t ws_size,
                              hipStream_t stream) {
  const float* x        = (const float*)d_in[0];
  const float* W_router = (const float*)d_in[1];
  const float* W_kv     = (const float*)d_in[2];
  const float* W_beta   = (const float*)d_in[3];
  const float* b_beta   = (const float*)d_in[4];
  const float* W_q      = (const float*)d_in[5];

  float* out  = (float*)d_out;
  float* Sfin = out + (size_t)TOK*NS;
  float* ws     = (float*)d_ws;
  float* logits = ws + WS_LOGITS;
  float* wsm    = ws + WS_W;
  float* qb     = ws + WS_Q;
  int*   selp   = (int*)(ws + WS_SEL);
  int*   toklist= (int*)(ws + WS_TOKL);
  int*   sellist= (int*)(ws + WS_SELL);
  int*   cnt    = (int*)(ws + WS_CNT);
  int*   tile   = (int*)(ws + WS_TILE);
  float* kvsel  = ws + WS_KVSEL;
  short* Whi    = (short*)(ws + WS_WHI);
  short* Wlo    = (short*)(ws + WS_WLO);

  hipMemsetAsync(out, 0, (size_t)TOK*NS*sizeof(float), stream);
  hipMemsetAsync(cnt, 0, 16*sizeof(int), stream);

  logits_kernel<<<TOK/64, 256, 0, stream>>>(x, W_router, logits);
  sgemm_kernel<<<dim3(TOK/64, 1), 256, 0, stream>>>(x, W_q, qb, NS, DIM);
  wcast_kernel<<<NB*192, 256, 0, stream>>>(W_kv, W_beta, Whi, Wlo);
  route_kernel<<<TOK/256, 256, 0, stream>>>(logits, wsm, selp, toklist, sellist, cnt);
  prefix_kernel<<<1, 256, 0, stream>>>(cnt, tile, toklist, sellist);
  gather_gemm_kernel<<<MAXTILES, 256, 0, stream>>>(
      x, Whi, Wlo, b_beta, tile, toklist, sellist, kvsel);
  recur_kernel<<<(BATCH*NB)/4, 256, 0, stream>>>(selp, wsm, kvsel, qb, out, Sfin);
}